// Round 1
// baseline (130.756 us; speedup 1.0000x reference)
//
#include <hip/hip_runtime.h>
#include <math.h>

#define LSEQ 256
#define HDIM 256

// ---------------- Phase 1: projections + abs_pos fold ----------------
// Q = queries@Wq^T + bq
// Keff = keys@Wk^T + bk + abs_pos_K
// Veff = values@Wv^T + bv + abs_pos_V
__global__ __launch_bounds__(256) void proj_kernel(
    const float* __restrict__ queries, const float* __restrict__ keys,
    const float* __restrict__ values,
    const float* __restrict__ apK, const float* __restrict__ apV,
    const float* __restrict__ Wq, const float* __restrict__ bq,
    const float* __restrict__ Wk, const float* __restrict__ bk,
    const float* __restrict__ Wv, const float* __restrict__ bv,
    float* __restrict__ Qo, float* __restrict__ Ko, float* __restrict__ Vo)
{
    const int R = 4;
    int tid = threadIdx.x;
    int row0 = blockIdx.x * R;

    float aq[R] = {0.f, 0.f, 0.f, 0.f};
    float ak[R] = {0.f, 0.f, 0.f, 0.f};
    float av[R] = {0.f, 0.f, 0.f, 0.f};

    const float* wq = Wq + tid * HDIM;
    const float* wk = Wk + tid * HDIM;
    const float* wv = Wv + tid * HDIM;

    for (int i = 0; i < HDIM; i += 4) {
        float4 wq4 = *(const float4*)(wq + i);
        float4 wk4 = *(const float4*)(wk + i);
        float4 wv4 = *(const float4*)(wv + i);
        #pragma unroll
        for (int r = 0; r < R; ++r) {
            float4 xq = *(const float4*)(queries + (row0 + r) * HDIM + i);
            float4 xk = *(const float4*)(keys    + (row0 + r) * HDIM + i);
            float4 xv = *(const float4*)(values  + (row0 + r) * HDIM + i);
            aq[r] += xq.x * wq4.x + xq.y * wq4.y + xq.z * wq4.z + xq.w * wq4.w;
            ak[r] += xk.x * wk4.x + xk.y * wk4.y + xk.z * wk4.z + xk.w * wk4.w;
            av[r] += xv.x * wv4.x + xv.y * wv4.y + xv.z * wv4.z + xv.w * wv4.w;
        }
    }
    #pragma unroll
    for (int r = 0; r < R; ++r) {
        int idx = (row0 + r) * HDIM + tid;
        Qo[idx] = aq[r] + bq[tid];
        Ko[idx] = ak[r] + bk[tid] + apK[idx];
        Vo[idx] = av[r] + bv[tid] + apV[idx];
    }
}

// ---------------- Phase 2: fused scores + softmax + PV ----------------
// One block per (b, q) row. 256 threads = 4 waves.
// Wave w handles k in [w*64, w*64+64) for scores and PV.
// Output element t = h*64+d matches the [B,L,H] layout directly.
__global__ __launch_bounds__(256) void attn_kernel(
    const float* __restrict__ Q, const float* __restrict__ Keff,
    const float* __restrict__ Veff,
    const float* __restrict__ tK, const float* __restrict__ tV,
    const int* __restrict__ tmask, float* __restrict__ out)
{
    __shared__ float sc[4][260];    // padded: head rows start 4 banks apart
    __shared__ float outp[4][256];

    int bq = blockIdx.x;
    int b = bq >> 8;
    int q = bq & 255;
    int tid = threadIdx.x;
    int w = tid >> 6;
    int lane = tid & 63;
    int head = lane >> 4;           // out element (lane*4..lane*4+3) belongs to this head

    bool masked = tmask[bq] != 0;   // entire row -> NEG -> uniform attn over ALL k

    const float* tKr = tK + (size_t)bq * (LSEQ * HDIM);
    const float* tVr = tV + (size_t)bq * (LSEQ * HDIM);
    const float* Kb = Keff + b * (LSEQ * HDIM);
    const float* Vb = Veff + b * (LSEQ * HDIM);

    if (!masked) {
        float4 q4 = *(const float4*)(Q + bq * HDIM + lane * 4);
        // scores: only k <= q ever matter (future mask -> exact zeros)
        int kend = min(w * 64 + 64, q + 1);   // exclusive
        #pragma unroll 2
        for (int k = w * 64; k < kend; ++k) {
            float4 t4 = *(const float4*)(tKr + k * HDIM + lane * 4);
            float4 k4 = *(const float4*)(Kb + k * HDIM + lane * 4);
            float s = q4.x * (t4.x + k4.x) + q4.y * (t4.y + k4.y)
                    + q4.z * (t4.z + k4.z) + q4.w * (t4.w + k4.w);
            s += __shfl_xor(s, 1);
            s += __shfl_xor(s, 2);
            s += __shfl_xor(s, 4);
            s += __shfl_xor(s, 8);
            if ((lane & 15) == 0) sc[head][k] = s * 0.125f;   // /sqrt(64)
        }
        __syncthreads();
        // softmax: wave w handles head w over all 256 k (invalid -> -inf)
        {
            int k0 = lane * 4;
            float4 v = *(const float4*)(&sc[w][k0]);
            float x0 = (k0 + 0 <= q) ? v.x : -INFINITY;
            float x1 = (k0 + 1 <= q) ? v.y : -INFINITY;
            float x2 = (k0 + 2 <= q) ? v.z : -INFINITY;
            float x3 = (k0 + 3 <= q) ? v.w : -INFINITY;
            float m = fmaxf(fmaxf(x0, x1), fmaxf(x2, x3));
            #pragma unroll
            for (int off = 32; off >= 1; off >>= 1)
                m = fmaxf(m, __shfl_xor(m, off));
            float e0 = __expf(x0 - m);
            float e1 = __expf(x1 - m);
            float e2 = __expf(x2 - m);
            float e3 = __expf(x3 - m);
            float ssum = e0 + e1 + e2 + e3;
            #pragma unroll
            for (int off = 32; off >= 1; off >>= 1)
                ssum += __shfl_xor(ssum, off);
            float inv = 1.0f / ssum;
            float4 a4 = make_float4(e0 * inv, e1 * inv, e2 * inv, e3 * inv);
            *(float4*)(&sc[w][k0]) = a4;
        }
        __syncthreads();
    }

    // PV: out[t] = sum_k attn[head(t)][k] * (Veff[b,k,t] + tV[b,q,k,t])
    float4 acc = make_float4(0.f, 0.f, 0.f, 0.f);
    int kmax = masked ? (LSEQ - 1) : q;          // inclusive
    int kend = min(w * 64 + 63, kmax);
    const float uw = 1.0f / 256.0f;              // uniform weight for masked rows
    #pragma unroll 4
    for (int k = w * 64; k <= kend; ++k) {
        float a = masked ? uw : sc[head][k];
        float4 t4 = *(const float4*)(tVr + k * HDIM + lane * 4);
        float4 v4 = *(const float4*)(Vb + k * HDIM + lane * 4);
        acc.x += a * (t4.x + v4.x);
        acc.y += a * (t4.y + v4.y);
        acc.z += a * (t4.z + v4.z);
        acc.w += a * (t4.w + v4.w);
    }
    *(float4*)(&outp[w][lane * 4]) = acc;
    __syncthreads();
    float o = outp[0][tid] + outp[1][tid] + outp[2][tid] + outp[3][tid];
    out[bq * HDIM + tid] = o;
}

extern "C" void kernel_launch(void* const* d_in, const int* in_sizes, int n_in,
                              void* d_out, int out_size, void* d_ws, size_t ws_size,
                              hipStream_t stream) {
    const float* queries = (const float*)d_in[0];
    const float* keys    = (const float*)d_in[1];
    const float* values  = (const float*)d_in[2];
    const float* tK      = (const float*)d_in[3];
    const float* tV      = (const float*)d_in[4];
    const float* apK     = (const float*)d_in[5];
    const float* apV     = (const float*)d_in[6];
    const int*   tmask   = (const int*)d_in[7];
    // d_in[8] future_time_mask: computed analytically (k > q), not read
    const float* Wq = (const float*)d_in[9];
    const float* bq = (const float*)d_in[10];
    const float* Wk = (const float*)d_in[11];
    const float* bk = (const float*)d_in[12];
    const float* Wv = (const float*)d_in[13];
    const float* bv = (const float*)d_in[14];

    float* ws = (float*)d_ws;
    float* Qo = ws;                 // [1024][256]
    float* Ko = ws + 262144;        // Keff = K + pK
    float* Vo = ws + 524288;        // Veff = V + pV
    float* out = (float*)d_out;

    proj_kernel<<<256, 256, 0, stream>>>(queries, keys, values, apK, apV,
                                         Wq, bq, Wk, bk, Wv, bv, Qo, Ko, Vo);
    attn_kernel<<<1024, 256, 0, stream>>>(Qo, Ko, Vo, tK, tV, tmask, out);
}

// Round 2
// 110.810 us; speedup vs baseline: 1.1800x; 1.1800x over previous
//
#include <hip/hip_runtime.h>
#include <math.h>

#define LSEQ 256
#define HDIM 256

// ---------------- Phase 1: projections + abs_pos fold ----------------
__global__ __launch_bounds__(256) void proj_kernel(
    const float* __restrict__ queries, const float* __restrict__ keys,
    const float* __restrict__ values,
    const float* __restrict__ apK, const float* __restrict__ apV,
    const float* __restrict__ Wq, const float* __restrict__ bq,
    const float* __restrict__ Wk, const float* __restrict__ bk,
    const float* __restrict__ Wv, const float* __restrict__ bv,
    float* __restrict__ Qo, float* __restrict__ Ko, float* __restrict__ Vo)
{
    const int R = 4;
    int tid = threadIdx.x;
    int row0 = blockIdx.x * R;

    float aq[R] = {0.f, 0.f, 0.f, 0.f};
    float ak[R] = {0.f, 0.f, 0.f, 0.f};
    float av[R] = {0.f, 0.f, 0.f, 0.f};

    const float* wq = Wq + tid * HDIM;
    const float* wk = Wk + tid * HDIM;
    const float* wv = Wv + tid * HDIM;

    #pragma unroll 2
    for (int i = 0; i < HDIM; i += 4) {
        float4 wq4 = *(const float4*)(wq + i);
        float4 wk4 = *(const float4*)(wk + i);
        float4 wv4 = *(const float4*)(wv + i);
        #pragma unroll
        for (int r = 0; r < R; ++r) {
            float4 xq = *(const float4*)(queries + (row0 + r) * HDIM + i);
            float4 xk = *(const float4*)(keys    + (row0 + r) * HDIM + i);
            float4 xv = *(const float4*)(values  + (row0 + r) * HDIM + i);
            aq[r] += xq.x * wq4.x + xq.y * wq4.y + xq.z * wq4.z + xq.w * wq4.w;
            ak[r] += xk.x * wk4.x + xk.y * wk4.y + xk.z * wk4.z + xk.w * wk4.w;
            av[r] += xv.x * wv4.x + xv.y * wv4.y + xv.z * wv4.z + xv.w * wv4.w;
        }
    }
    #pragma unroll
    for (int r = 0; r < R; ++r) {
        int idx = (row0 + r) * HDIM + tid;
        Qo[idx] = aq[r] + bq[tid];
        Ko[idx] = ak[r] + bk[tid] + apK[idx];
        Vo[idx] = av[r] + bv[tid] + apV[idx];
    }
}

// ---------------- Phase 2: fused scores + softmax + PV ----------------
// 512 threads = 8 waves per block, one block per (b,q).
// k distributed across waves with stride 8 (wave w: k = w, w+8, ...).
__device__ __forceinline__ float dot4(float4 a, float4 b) {
    return a.x * b.x + a.y * b.y + a.z * b.z + a.w * b.w;
}

__global__ __launch_bounds__(512, 6) void attn_kernel(
    const float* __restrict__ Q, const float* __restrict__ Keff,
    const float* __restrict__ Veff,
    const float* __restrict__ tK, const float* __restrict__ tV,
    const int* __restrict__ tmask, float* __restrict__ out)
{
    __shared__ float sc[4][260];    // head rows offset by 4 banks
    __shared__ float outp[8][256];

    int bid = blockIdx.x;
    int b = bid >> 8;
    int ii = bid & 255;
    // pair light (low q) with heavy (high q) blocks for load balance
    int q = (ii & 1) ? (255 - (ii >> 1)) : (ii >> 1);
    int bq = (b << 8) | q;

    int tid = threadIdx.x;
    int w = tid >> 6;
    int lane = tid & 63;
    int head = lane >> 4;

    bool masked = tmask[bq] != 0;   // whole row NEG -> exactly uniform attn

    const float* tKr = tK + (size_t)bq * (LSEQ * HDIM);
    const float* tVr = tV + (size_t)bq * (LSEQ * HDIM);
    const float* Kb = Keff + b * (LSEQ * HDIM);
    const float* Vb = Veff + b * (LSEQ * HDIM);
    const int le4 = lane * 4;

    if (!masked) {
        float4 q4 = *(const float4*)(Q + bq * HDIM + le4);
        // scores for k <= q only (future positions give exact-0 softmax)
        int k = w;
        #pragma unroll 2
        for (; k + 8 <= q; k += 16) {
            float4 ta = *(const float4*)(tKr + k * HDIM + le4);
            float4 ka = *(const float4*)(Kb + k * HDIM + le4);
            float4 tb = *(const float4*)(tKr + (k + 8) * HDIM + le4);
            float4 kb2 = *(const float4*)(Kb + (k + 8) * HDIM + le4);
            float s0 = dot4(q4, make_float4(ta.x + ka.x, ta.y + ka.y, ta.z + ka.z, ta.w + ka.w));
            float s1 = dot4(q4, make_float4(tb.x + kb2.x, tb.y + kb2.y, tb.z + kb2.z, tb.w + kb2.w));
            s0 += __shfl_xor(s0, 1);  s1 += __shfl_xor(s1, 1);
            s0 += __shfl_xor(s0, 2);  s1 += __shfl_xor(s1, 2);
            s0 += __shfl_xor(s0, 4);  s1 += __shfl_xor(s1, 4);
            s0 += __shfl_xor(s0, 8);  s1 += __shfl_xor(s1, 8);
            if ((lane & 15) == 0) {
                sc[head][k] = s0 * 0.125f;       // /sqrt(64)
                sc[head][k + 8] = s1 * 0.125f;
            }
        }
        if (k <= q) {
            float4 ta = *(const float4*)(tKr + k * HDIM + le4);
            float4 ka = *(const float4*)(Kb + k * HDIM + le4);
            float s0 = dot4(q4, make_float4(ta.x + ka.x, ta.y + ka.y, ta.z + ka.z, ta.w + ka.w));
            s0 += __shfl_xor(s0, 1);
            s0 += __shfl_xor(s0, 2);
            s0 += __shfl_xor(s0, 4);
            s0 += __shfl_xor(s0, 8);
            if ((lane & 15) == 0) sc[head][k] = s0 * 0.125f;
        }
        __syncthreads();
        if (w < 4) {  // wave w: softmax over head w
            int k0 = lane * 4;
            float4 v = *(const float4*)(&sc[w][k0]);
            float x0 = (k0 + 0 <= q) ? v.x : -INFINITY;
            float x1 = (k0 + 1 <= q) ? v.y : -INFINITY;
            float x2 = (k0 + 2 <= q) ? v.z : -INFINITY;
            float x3 = (k0 + 3 <= q) ? v.w : -INFINITY;
            float m = fmaxf(fmaxf(x0, x1), fmaxf(x2, x3));
            #pragma unroll
            for (int off = 32; off >= 1; off >>= 1)
                m = fmaxf(m, __shfl_xor(m, off));
            float e0 = __expf(x0 - m);
            float e1 = __expf(x1 - m);
            float e2 = __expf(x2 - m);
            float e3 = __expf(x3 - m);
            float ssum = e0 + e1 + e2 + e3;
            #pragma unroll
            for (int off = 32; off >= 1; off >>= 1)
                ssum += __shfl_xor(ssum, off);
            float inv = 1.0f / ssum;
            *(float4*)(&sc[w][k0]) = make_float4(e0 * inv, e1 * inv, e2 * inv, e3 * inv);
        }
        __syncthreads();
    }

    // PV: out[t] = sum_k a[head][k] * (Veff[b,k,t] + tV[b,q,k,t])
    float4 acc = make_float4(0.f, 0.f, 0.f, 0.f);
    int kmax = masked ? (LSEQ - 1) : q;     // inclusive
    const float uw = 1.0f / 256.0f;
    int k = w;
    #pragma unroll 2
    for (; k + 8 <= kmax; k += 16) {
        float a0 = masked ? uw : sc[head][k];
        float a1 = masked ? uw : sc[head][k + 8];
        float4 t0 = *(const float4*)(tVr + k * HDIM + le4);
        float4 v0 = *(const float4*)(Vb + k * HDIM + le4);
        float4 t1 = *(const float4*)(tVr + (k + 8) * HDIM + le4);
        float4 v1 = *(const float4*)(Vb + (k + 8) * HDIM + le4);
        acc.x += a0 * (t0.x + v0.x) + a1 * (t1.x + v1.x);
        acc.y += a0 * (t0.y + v0.y) + a1 * (t1.y + v1.y);
        acc.z += a0 * (t0.z + v0.z) + a1 * (t1.z + v1.z);
        acc.w += a0 * (t0.w + v0.w) + a1 * (t1.w + v1.w);
    }
    if (k <= kmax) {
        float a0 = masked ? uw : sc[head][k];
        float4 t0 = *(const float4*)(tVr + k * HDIM + le4);
        float4 v0 = *(const float4*)(Vb + k * HDIM + le4);
        acc.x += a0 * (t0.x + v0.x);
        acc.y += a0 * (t0.y + v0.y);
        acc.z += a0 * (t0.z + v0.z);
        acc.w += a0 * (t0.w + v0.w);
    }
    *(float4*)(&outp[w][le4]) = acc;
    __syncthreads();
    if (tid < 256) {
        float o = 0.f;
        #pragma unroll
        for (int p = 0; p < 8; ++p) o += outp[p][tid];
        out[bq * HDIM + tid] = o;
    }
}

extern "C" void kernel_launch(void* const* d_in, const int* in_sizes, int n_in,
                              void* d_out, int out_size, void* d_ws, size_t ws_size,
                              hipStream_t stream) {
    const float* queries = (const float*)d_in[0];
    const float* keys    = (const float*)d_in[1];
    const float* values  = (const float*)d_in[2];
    const float* tK      = (const float*)d_in[3];
    const float* tV      = (const float*)d_in[4];
    const float* apK     = (const float*)d_in[5];
    const float* apV     = (const float*)d_in[6];
    const int*   tmask   = (const int*)d_in[7];
    // d_in[8] future_time_mask: analytic (k > q), never read
    const float* Wq = (const float*)d_in[9];
    const float* bq = (const float*)d_in[10];
    const float* Wk = (const float*)d_in[11];
    const float* bk = (const float*)d_in[12];
    const float* Wv = (const float*)d_in[13];
    const float* bv = (const float*)d_in[14];

    float* ws = (float*)d_ws;
    float* Qo = ws;                 // [1024][256]
    float* Ko = ws + 262144;        // Keff = K + bk + pK
    float* Vo = ws + 524288;        // Veff = V + bv + pV
    float* out = (float*)d_out;

    proj_kernel<<<256, 256, 0, stream>>>(queries, keys, values, apK, apV,
                                         Wq, bq, Wk, bk, Wv, bv, Qo, Ko, Vo);
    attn_kernel<<<1024, 512, 0, stream>>>(Qo, Ko, Vo, tK, tV, tmask, out);
}